// Round 1
// baseline (207.519 us; speedup 1.0000x reference)
//
#include <hip/hip_runtime.h>
#include <hip/hip_bf16.h>
#include <cstdint>
#include <cstddef>

// ---------------------------------------------------------------------------
// ThreeLayerFCModel: out = relu(relu(relu(x@w0^T+b0)@(w1*m1)^T+b1)@(w2*m2)^T+b2)
// B=16384, all dims 1024. Strategy: fold masks into weights, cast to bf16,
// run three m97-structure MFMA GEMMs (128x128 tile, BK=32, global_load_lds).
// ---------------------------------------------------------------------------

typedef __bf16 bf16x8 __attribute__((ext_vector_type(8)));
typedef float  f32x4  __attribute__((ext_vector_type(4)));

#define AS1 __attribute__((address_space(1)))
#define AS3 __attribute__((address_space(3)))

__device__ __forceinline__ void gload_lds16(const void* g, void* l) {
    __builtin_amdgcn_global_load_lds((const AS1 void*)g, (AS3 void*)l, 16, 0, 0);
}

// ---------------------------------------------------------------------------
// Mask dtype detection. mask1 is 90% ones; depending on harness marshalling it
// may arrive as uint8 (bool), int32, or float32. Probe byte lanes of first 1KB:
//   uint8 : bytes at pos%4==1 are mask values -> mostly 1  -> mode 1
//   int32 : only pos%4==0 can be nonzero                    -> mode 0
//   f32   : 1.0f = 00 00 80 3f -> pos%4==3 nonzero, %4==1 0 -> mode 2
// ---------------------------------------------------------------------------
__global__ void detect_mask(const unsigned char* __restrict__ m, int* __restrict__ flag) {
    if (threadIdx.x != 0 || blockIdx.x != 0) return;
    int or1 = 0, or3 = 0;
    for (int e = 0; e < 256; ++e) {
        or1 |= m[e * 4 + 1];
        or3 |= m[e * 4 + 3];
    }
    *flag = or1 ? 1 : (or3 ? 2 : 0);
}

// x (fp32) -> bf16, 8 elements/thread
__global__ void cvt_bf16(const float* __restrict__ in, __bf16* __restrict__ out, long n) {
    long i = ((long)blockIdx.x * blockDim.x + threadIdx.x) * 8;
    if (i >= n) return;
    float4 a = *reinterpret_cast<const float4*>(in + i);
    float4 b = *reinterpret_cast<const float4*>(in + i + 4);
    bf16x8 o;
    o[0] = (__bf16)a.x; o[1] = (__bf16)a.y; o[2] = (__bf16)a.z; o[3] = (__bf16)a.w;
    o[4] = (__bf16)b.x; o[5] = (__bf16)b.y; o[6] = (__bf16)b.z; o[7] = (__bf16)b.w;
    *reinterpret_cast<bf16x8*>(out + i) = o;
}

// weight * mask -> bf16 (mask may be null / uint8 / int32 / f32 per flag)
__global__ void prep_w(const float* __restrict__ w, const void* __restrict__ mask,
                       const int* __restrict__ flag, __bf16* __restrict__ out, long n) {
    long i = ((long)blockIdx.x * blockDim.x + threadIdx.x) * 8;
    if (i >= n) return;
    float4 a = *reinterpret_cast<const float4*>(w + i);
    float4 b = *reinterpret_cast<const float4*>(w + i + 4);
    float v[8] = {a.x, a.y, a.z, a.w, b.x, b.y, b.z, b.w};
    if (mask) {
        const int mode = *flag;
        if (mode == 1) {
            const unsigned char* mp = (const unsigned char*)mask;
            #pragma unroll
            for (int j = 0; j < 8; ++j) v[j] = mp[i + j] ? v[j] : 0.f;
        } else if (mode == 0) {
            const int* mp = (const int*)mask;
            #pragma unroll
            for (int j = 0; j < 8; ++j) v[j] = mp[i + j] ? v[j] : 0.f;
        } else {
            const float* mp = (const float*)mask;
            #pragma unroll
            for (int j = 0; j < 8; ++j) v[j] = (mp[i + j] != 0.f) ? v[j] : 0.f;
        }
    }
    bf16x8 o;
    #pragma unroll
    for (int j = 0; j < 8; ++j) o[j] = (__bf16)v[j];
    *reinterpret_cast<bf16x8*>(out + i) = o;
}

// ---------------------------------------------------------------------------
// GEMM: C[M,N] = relu(A[M,K] * W[N,K]^T + bias), M=16384, N=K=1024.
// m97 structure: 128x128 tile, BK=32, 256 threads = 4 waves in 2x2,
// each wave 64x64 = 4x4 fragments of mfma_f32_16x16x32_bf16.
// ---------------------------------------------------------------------------
template<bool F32OUT>
__global__ __launch_bounds__(256) void gemm_relu(
    const __bf16* __restrict__ A, const __bf16* __restrict__ W,
    const float* __restrict__ bias,
    __bf16* __restrict__ outb, float* __restrict__ outf) {
    constexpr int N = 1024, K = 1024, BK = 32;

    __shared__ __bf16 lA[128 * BK];  // 8 KiB
    __shared__ __bf16 lB[128 * BK];  // 8 KiB

    const int t    = threadIdx.x;
    const int lane = t & 63;
    const int wave = t >> 6;
    const int wr   = wave >> 1;        // 0..1
    const int wc   = wave & 1;         // 0..1
    const int l15  = lane & 15;
    const int hi   = lane >> 4;        // 0..3
    const int brow = blockIdx.y * 128;
    const int bcol = blockIdx.x * 128;

    // global_load_lds staging: thread t covers LDS bytes [t*16, t*16+16) per
    // round; row = t/4 (+64 in round 1), col = (t&3)*8. Linear LDS layout.
    const __bf16* gA = A + (size_t)(brow + (t >> 2)) * K + (t & 3) * 8;
    const __bf16* gW = W + (size_t)(bcol + (t >> 2)) * K + (t & 3) * 8;
    __bf16* lA_w = &lA[(t & 192) * 8];  // wave-uniform base (wave*1024 bytes)
    __bf16* lB_w = &lB[(t & 192) * 8];

    const int aoff = (wr * 64 + l15) * BK + hi * 8;
    const int boff = (wc * 64 + l15) * BK + hi * 8;

    f32x4 acc[4][4] = {};

    for (int k0 = 0; k0 < K; k0 += BK) {
        gload_lds16(gA,          lA_w);
        gload_lds16(gA + 64 * K, lA_w + 2048);
        gload_lds16(gW,          lB_w);
        gload_lds16(gW + 64 * K, lB_w + 2048);
        gA += BK; gW += BK;
        __syncthreads();  // drains vmcnt: staged tile visible

        bf16x8 a[4], b[4];
        #pragma unroll
        for (int m = 0; m < 4; ++m)
            a[m] = *reinterpret_cast<const bf16x8*>(&lA[aoff + m * 16 * BK]);
        #pragma unroll
        for (int n = 0; n < 4; ++n)
            b[n] = *reinterpret_cast<const bf16x8*>(&lB[boff + n * 16 * BK]);

        #pragma unroll
        for (int m = 0; m < 4; ++m)
            #pragma unroll
            for (int n = 0; n < 4; ++n)
                acc[m][n] = __builtin_amdgcn_mfma_f32_16x16x32_bf16(
                    a[m], b[n], acc[m][n], 0, 0, 0);
        __syncthreads();  // protect tile from next iteration's staging
    }

    // Epilogue: C/D layout (m89-verified): col = lane&15, row = (lane>>4)*4 + reg
    #pragma unroll
    for (int n = 0; n < 4; ++n) {
        const int col = bcol + wc * 64 + n * 16 + l15;
        const float bv = bias[col];
        #pragma unroll
        for (int m = 0; m < 4; ++m) {
            const int row0 = brow + wr * 64 + m * 16 + hi * 4;
            #pragma unroll
            for (int r = 0; r < 4; ++r) {
                float v = acc[m][n][r] + bv;
                v = v > 0.f ? v : 0.f;
                if constexpr (F32OUT)
                    outf[(size_t)(row0 + r) * N + col] = v;
                else
                    outb[(size_t)(row0 + r) * N + col] = (__bf16)v;
            }
        }
    }
}

// ---------------------------------------------------------------------------
extern "C" void kernel_launch(void* const* d_in, const int* in_sizes, int n_in,
                              void* d_out, int out_size, void* d_ws, size_t ws_size,
                              hipStream_t stream) {
    const float* x  = (const float*)d_in[0];
    const float* w0 = (const float*)d_in[1];
    const float* b0 = (const float*)d_in[2];
    const float* w1 = (const float*)d_in[3];
    const float* b1 = (const float*)d_in[4];
    const void*  m1 = d_in[5];
    const float* w2 = (const float*)d_in[6];
    const float* b2 = (const float*)d_in[7];
    const void*  m2 = d_in[8];
    float* out = (float*)d_out;

    char* ws = (char*)d_ws;
    __bf16* xb  = (__bf16*)(ws);                                  // 32 MiB (x, later h2)
    __bf16* h1  = (__bf16*)(ws + (size_t)32 * 1024 * 1024);       // 32 MiB
    __bf16* w0b = (__bf16*)(ws + (size_t)64 * 1024 * 1024);       // 2 MiB
    __bf16* w1b = w0b + 1024 * 1024;                              // 2 MiB
    __bf16* w2b = w1b + 1024 * 1024;                              // 2 MiB
    int*   flag = (int*)(w2b + 1024 * 1024);

    detect_mask<<<1, 64, 0, stream>>>((const unsigned char*)m1, flag);
    cvt_bf16<<<8192, 256, 0, stream>>>(x, xb, 16384L * 1024);
    prep_w<<<512, 256, 0, stream>>>(w0, nullptr, flag, w0b, 1024L * 1024);
    prep_w<<<512, 256, 0, stream>>>(w1, m1,      flag, w1b, 1024L * 1024);
    prep_w<<<512, 256, 0, stream>>>(w2, m2,      flag, w2b, 1024L * 1024);

    dim3 grid(8, 128);  // N/128 x M/128
    gemm_relu<false><<<grid, 256, 0, stream>>>(xb, w0b, b0, h1, nullptr);
    gemm_relu<false><<<grid, 256, 0, stream>>>(h1, w1b, b1, xb, nullptr);  // h2 -> xb
    gemm_relu<true ><<<grid, 256, 0, stream>>>(xb, w2b, b2, nullptr, out);
}

// Round 2
// 135.747 us; speedup vs baseline: 1.5287x; 1.5287x over previous
//
#include <hip/hip_runtime.h>
#include <hip/hip_bf16.h>
#include <cstdint>
#include <cstddef>

// ---------------------------------------------------------------------------
// ThreeLayerFCModel: out = relu(relu(relu(x@w0^T+b0)@(w1*m1)^T+b1)@(w2*m2)^T+b2)
// B=16384, dims 1024. Masks folded into bf16 weights; three 256x256-tile
// 8-phase MFMA GEMMs (T1 XCD swizzle + T2 LDS XOR swizzle + T3/T4 counted
// vmcnt pipeline + T5 setprio).
// ---------------------------------------------------------------------------

typedef __bf16 bf16x8 __attribute__((ext_vector_type(8)));
typedef float  f32x4  __attribute__((ext_vector_type(4)));

#define AS1 __attribute__((address_space(1)))
#define AS3 __attribute__((address_space(3)))

__device__ __forceinline__ void gload_lds16(const void* g, void* l) {
    __builtin_amdgcn_global_load_lds((const AS1 void*)g, (AS3 void*)l, 16, 0, 0);
}

// ---------------- mask dtype detection (uint8 / int32 / f32) ----------------
__global__ void detect_mask(const unsigned char* __restrict__ m, int* __restrict__ flag) {
    if (threadIdx.x != 0 || blockIdx.x != 0) return;
    int or1 = 0, or3 = 0;
    for (int e = 0; e < 256; ++e) { or1 |= m[e * 4 + 1]; or3 |= m[e * 4 + 3]; }
    *flag = or1 ? 1 : (or3 ? 2 : 0);
}

__global__ void cvt_bf16(const float* __restrict__ in, __bf16* __restrict__ out, long n) {
    long i = ((long)blockIdx.x * blockDim.x + threadIdx.x) * 8;
    if (i >= n) return;
    float4 a = *reinterpret_cast<const float4*>(in + i);
    float4 b = *reinterpret_cast<const float4*>(in + i + 4);
    bf16x8 o;
    o[0] = (__bf16)a.x; o[1] = (__bf16)a.y; o[2] = (__bf16)a.z; o[3] = (__bf16)a.w;
    o[4] = (__bf16)b.x; o[5] = (__bf16)b.y; o[6] = (__bf16)b.z; o[7] = (__bf16)b.w;
    *reinterpret_cast<bf16x8*>(out + i) = o;
}

__global__ void prep_w(const float* __restrict__ w, const void* __restrict__ mask,
                       const int* __restrict__ flag, __bf16* __restrict__ out, long n) {
    long i = ((long)blockIdx.x * blockDim.x + threadIdx.x) * 8;
    if (i >= n) return;
    float4 a = *reinterpret_cast<const float4*>(w + i);
    float4 b = *reinterpret_cast<const float4*>(w + i + 4);
    float v[8] = {a.x, a.y, a.z, a.w, b.x, b.y, b.z, b.w};
    if (mask) {
        const int mode = *flag;
        if (mode == 1) {
            const unsigned char* mp = (const unsigned char*)mask;
            #pragma unroll
            for (int j = 0; j < 8; ++j) v[j] = mp[i + j] ? v[j] : 0.f;
        } else if (mode == 0) {
            const int* mp = (const int*)mask;
            #pragma unroll
            for (int j = 0; j < 8; ++j) v[j] = mp[i + j] ? v[j] : 0.f;
        } else {
            const float* mp = (const float*)mask;
            #pragma unroll
            for (int j = 0; j < 8; ++j) v[j] = (mp[i + j] != 0.f) ? v[j] : 0.f;
        }
    }
    bf16x8 o;
    #pragma unroll
    for (int j = 0; j < 8; ++j) o[j] = (__bf16)v[j];
    *reinterpret_cast<bf16x8*>(out + i) = o;
}

// ---------------------------------------------------------------------------
// 256x256-tile 8-phase GEMM: C = relu(A[16384,1024] * W[1024,1024]^T + bias)
// 512 thr = 8 waves (2 row x 4 col), per-wave 128x64 out, BK=64, 16 K-tiles.
// LDS 128 KiB: A[2 dbuf][2 half][128 rows][64 k], B same. Half-tile = 16 KiB
// = 512 thr x 2 gload_lds16. XOR swizzle byte^=((row&7)<<4) on source+read.
// Pipeline: A(t+1) staged during tile t (ph0,ph1); B(t+2) during tile t
// (ph1,ph2); boundary wait vmcnt(4) (B(t+2)'s 4 gloads may stay in flight).
// ---------------------------------------------------------------------------
__device__ __forceinline__ f32x4 mfma16(bf16x8 a, bf16x8 b, f32x4 c) {
    return __builtin_amdgcn_mfma_f32_16x16x32_bf16(a, b, c, 0, 0, 0);
}

#define MFMAQ(Q, A00, A01, A10, A11)                                        \
    __builtin_amdgcn_s_setprio(1);                                          \
    _Pragma("unroll")                                                       \
    for (int n = 0; n < 4; ++n) {                                           \
        acc[2*(Q)][n]   = mfma16(A00, b[n][0], acc[2*(Q)][n]);              \
        acc[2*(Q)][n]   = mfma16(A01, b[n][1], acc[2*(Q)][n]);              \
        acc[2*(Q)+1][n] = mfma16(A10, b[n][0], acc[2*(Q)+1][n]);            \
        acc[2*(Q)+1][n] = mfma16(A11, b[n][1], acc[2*(Q)+1][n]);            \
    }                                                                       \
    __builtin_amdgcn_s_setprio(0);

#define BAR() __builtin_amdgcn_s_barrier(); __builtin_amdgcn_sched_barrier(0)

template<bool F32OUT>
__global__ __launch_bounds__(512, 2) void gemm8p(
    const __bf16* __restrict__ A, const __bf16* __restrict__ W,
    const float* __restrict__ bias,
    __bf16* __restrict__ outb, float* __restrict__ outf) {
    constexpr int NT = 16;  // K/64
    extern __shared__ char smem[];  // A: [0,64K), B: [64K,128K)

    const int t   = threadIdx.x;
    const int l   = t & 63, l15 = l & 15, lhi = l >> 4;
    const int w   = t >> 6, wr = w >> 2, wc = w & 3;

    // T1: bijective XCD swizzle (256 blocks % 8 == 0)
    const int bid = blockIdx.x;
    const int swz = (bid & 7) * 32 + (bid >> 3);
    const int bx = swz & 3, by = swz >> 2;
    const int brow = by * 256, bcol = bx * 256;

    // staging per-thread consts: linear LDS chunk (j*512+t)*16B; row=idx/8,
    // in-row byte (t&7)*16 XOR'd with ((row&7)<<4)  (T2 pre-swizzled source)
    const int srow = t >> 3;                                    // 0..63 (+64 for j=1; row&7 same)
    const int scol = (((t & 7) ^ ((t >> 3) & 7)) << 4) >> 1;    // element col
    const __bf16* gA = A + (size_t)(brow + srow) * 1024 + scol;
    const __bf16* gW = W + (size_t)(bcol + srow) * 1024 + scol;
    const int woff = (t & 448) * 16;                            // wave*1024 B (uniform/wave)

    char* const ldsA = smem;
    char* const ldsB = smem + 65536;

    auto stageA = [&](int d, int h, int k0) {
        const __bf16* g = gA + (size_t)h * 131072 + k0;         // h*128 rows
        char* p = ldsA + d * 32768 + h * 16384 + woff;
        gload_lds16(g, p);                                      // rows 0..63
        gload_lds16(g + 65536, p + 8192);                       // rows 64..127
    };
    auto stageB = [&](int d, int h, int k0) {
        const __bf16* g = gW + (size_t)h * 131072 + k0;
        char* p = ldsB + d * 32768 + h * 16384 + woff;
        gload_lds16(g, p);
        gload_lds16(g + 65536, p + 8192);
    };

    // fragment-read per-lane consts (T2 swizzled read addresses)
    const int xorm  = (l & 7) << 4;
    const int koff0 = (lhi * 16) ^ xorm;
    const int koff1 = (64 + lhi * 16) ^ xorm;
    char* const aBase = ldsA + wr * 16384 + l15 * 128;
    char* const bBase = ldsB + (wc >> 1) * 16384 + ((wc & 1) * 64 + l15) * 128;

    f32x4 acc[8][4] = {};

    // prologue: A0 (8 gloads... 4 instr/wave), B0, B1 -> 12 wave-instr total;
    // tile 0 needs oldest 8 -> vmcnt(4)
    stageA(0, 0, 0); stageA(0, 1, 0);
    stageB(0, 0, 0); stageB(0, 1, 0);
    stageB(1, 0, 64); stageB(1, 1, 64);
    asm volatile("s_waitcnt vmcnt(4)" ::: "memory");
    BAR();

    #pragma unroll 2
    for (int tt = 0; tt < NT; ++tt) {
        const int d  = tt & 1;
        const int k1 = (tt + 1) * 64, k2 = (tt + 2) * 64;
        char* const aB = aBase + d * 32768;
        char* const bB = bBase + d * 32768;

        // ---- phase 0: B frags (held all tile) + quadrant 0 ----
        bf16x8 b[4][2];
        #pragma unroll
        for (int n = 0; n < 4; ++n) {
            b[n][0] = *(const bf16x8*)(bB + n * 2048 + koff0);
            b[n][1] = *(const bf16x8*)(bB + n * 2048 + koff1);
        }
        bf16x8 a00 = *(const bf16x8*)(aB + 0 * 2048 + koff0);
        bf16x8 a01 = *(const bf16x8*)(aB + 0 * 2048 + koff1);
        bf16x8 a10 = *(const bf16x8*)(aB + 1 * 2048 + koff0);
        bf16x8 a11 = *(const bf16x8*)(aB + 1 * 2048 + koff1);
        if (tt + 1 < NT) stageA(d ^ 1, 0, k1);
        MFMAQ(0, a00, a01, a10, a11);
        BAR();

        // ---- phase 1: quadrant 1; stage A(t+1)h1, B(t+2)h0 ----
        a00 = *(const bf16x8*)(aB + 2 * 2048 + koff0);
        a01 = *(const bf16x8*)(aB + 2 * 2048 + koff1);
        a10 = *(const bf16x8*)(aB + 3 * 2048 + koff0);
        a11 = *(const bf16x8*)(aB + 3 * 2048 + koff1);
        if (tt + 1 < NT) stageA(d ^ 1, 1, k1);
        if (tt + 2 < NT) stageB(d, 0, k2);     // B slot of tile t: free after ph0
        MFMAQ(1, a00, a01, a10, a11);
        BAR();

        // ---- phase 2: quadrant 2; stage B(t+2)h1 ----
        a00 = *(const bf16x8*)(aB + 4 * 2048 + koff0);
        a01 = *(const bf16x8*)(aB + 4 * 2048 + koff1);
        a10 = *(const bf16x8*)(aB + 5 * 2048 + koff0);
        a11 = *(const bf16x8*)(aB + 5 * 2048 + koff1);
        if (tt + 2 < NT) stageB(d, 1, k2);
        MFMAQ(2, a00, a01, a10, a11);
        BAR();

        // ---- phase 3: quadrant 3; boundary counted wait ----
        a00 = *(const bf16x8*)(aB + 6 * 2048 + koff0);
        a01 = *(const bf16x8*)(aB + 6 * 2048 + koff1);
        a10 = *(const bf16x8*)(aB + 7 * 2048 + koff0);
        a11 = *(const bf16x8*)(aB + 7 * 2048 + koff1);
        MFMAQ(3, a00, a01, a10, a11);
        if (tt < NT - 1) {
            if (tt <= NT - 3) { asm volatile("s_waitcnt vmcnt(4)" ::: "memory"); }
            else              { asm volatile("s_waitcnt vmcnt(0)" ::: "memory"); }
            BAR();
        }
    }

    // ---- epilogue: C/D layout col=l&15, row=(l>>4)*4+reg ----
    const int orow = brow + wr * 128 + lhi * 4;
    const int ocol = bcol + wc * 64 + l15;
    #pragma unroll
    for (int n = 0; n < 4; ++n) {
        const int col = ocol + n * 16;
        const float bv = bias[col];
        #pragma unroll
        for (int m = 0; m < 8; ++m) {
            const int r0 = orow + m * 16;
            #pragma unroll
            for (int r = 0; r < 4; ++r) {
                float v = acc[m][n][r] + bv;
                v = v > 0.f ? v : 0.f;
                if constexpr (F32OUT) outf[(size_t)(r0 + r) * 1024 + col] = v;
                else                  outb[(size_t)(r0 + r) * 1024 + col] = (__bf16)v;
            }
        }
    }
}

// ---------------------------------------------------------------------------
extern "C" void kernel_launch(void* const* d_in, const int* in_sizes, int n_in,
                              void* d_out, int out_size, void* d_ws, size_t ws_size,
                              hipStream_t stream) {
    const float* x  = (const float*)d_in[0];
    const float* w0 = (const float*)d_in[1];
    const float* b0 = (const float*)d_in[2];
    const float* w1 = (const float*)d_in[3];
    const float* b1 = (const float*)d_in[4];
    const void*  m1 = d_in[5];
    const float* w2 = (const float*)d_in[6];
    const float* b2 = (const float*)d_in[7];
    const void*  m2 = d_in[8];
    float* out = (float*)d_out;

    char* ws = (char*)d_ws;
    __bf16* xb  = (__bf16*)(ws);                             // 32 MiB (x, later h2)
    __bf16* h1  = (__bf16*)(ws + (size_t)32 * 1024 * 1024);  // 32 MiB
    __bf16* w0b = (__bf16*)(ws + (size_t)64 * 1024 * 1024);
    __bf16* w1b = w0b + 1024 * 1024;
    __bf16* w2b = w1b + 1024 * 1024;
    int*   flag = (int*)(w2b + 1024 * 1024);

    hipFuncSetAttribute((const void*)gemm8p<false>,
                        hipFuncAttributeMaxDynamicSharedMemorySize, 131072);
    hipFuncSetAttribute((const void*)gemm8p<true>,
                        hipFuncAttributeMaxDynamicSharedMemorySize, 131072);

    detect_mask<<<1, 64, 0, stream>>>((const unsigned char*)m1, flag);
    cvt_bf16<<<8192, 256, 0, stream>>>(x, xb, 16384L * 1024);
    prep_w<<<512, 256, 0, stream>>>(w0, nullptr, flag, w0b, 1024L * 1024);
    prep_w<<<512, 256, 0, stream>>>(w1, m1,      flag, w1b, 1024L * 1024);
    prep_w<<<512, 256, 0, stream>>>(w2, m2,      flag, w2b, 1024L * 1024);

    gemm8p<false><<<256, 512, 131072, stream>>>(xb, w0b, b0, h1, nullptr);
    gemm8p<false><<<256, 512, 131072, stream>>>(h1, w1b, b1, xb, nullptr);  // h2 -> xb
    gemm8p<true ><<<256, 512, 131072, stream>>>(xb, w2b, b2, nullptr, out);
}

// Round 3
// 126.952 us; speedup vs baseline: 1.6346x; 1.0693x over previous
//
#include <hip/hip_runtime.h>
#include <hip/hip_bf16.h>
#include <cstdint>
#include <cstddef>

// ---------------------------------------------------------------------------
// ThreeLayerFCModel: out = relu(relu(relu(x@w0^T+b0)@(w1*m1)^T+b1)@(w2*m2)^T+b2)
// B=16384, dims 1024. Masks folded into bf16 weights; three 256x256-tile
// 8-phase MFMA GEMMs. Round 3: symmetric 2-tile lookahead (vmcnt(8)),
// coalesced LDS-restaged bf16 epilogue, fused prep kernel.
// ---------------------------------------------------------------------------

typedef __bf16 bf16x8 __attribute__((ext_vector_type(8)));
typedef float  f32x4  __attribute__((ext_vector_type(4)));

#define AS1 __attribute__((address_space(1)))
#define AS3 __attribute__((address_space(3)))

__device__ __forceinline__ void gload_lds16(const void* g, void* l) {
    __builtin_amdgcn_global_load_lds((const AS1 void*)g, (AS3 void*)l, 16, 0, 0);
}

// ---------------- mask dtype detection (uint8 / int32 / f32) ----------------
__global__ void detect_mask(const unsigned char* __restrict__ m, int* __restrict__ flag) {
    const int t = threadIdx.x;  // 64
    int or1 = 0, or3 = 0;
    for (int e = t; e < 256; e += 64) { or1 |= m[e * 4 + 1]; or3 |= m[e * 4 + 3]; }
    unsigned long long b1 = __ballot(or1 != 0);
    unsigned long long b3 = __ballot(or3 != 0);
    if (t == 0) *flag = b1 ? 1 : (b3 ? 2 : 0);
}

// ---------------- fused prep: cvt x->bf16 + 3x (w*mask)->bf16 ---------------
__device__ __forceinline__ void prep_body(const float* __restrict__ w,
                                          const void* __restrict__ mask, int mode,
                                          __bf16* __restrict__ out, long i) {
    float4 a = *reinterpret_cast<const float4*>(w + i);
    float4 b = *reinterpret_cast<const float4*>(w + i + 4);
    float v[8] = {a.x, a.y, a.z, a.w, b.x, b.y, b.z, b.w};
    if (mask) {
        if (mode == 1) {
            const unsigned char* mp = (const unsigned char*)mask;
            #pragma unroll
            for (int j = 0; j < 8; ++j) v[j] = mp[i + j] ? v[j] : 0.f;
        } else if (mode == 0) {
            const int* mp = (const int*)mask;
            #pragma unroll
            for (int j = 0; j < 8; ++j) v[j] = mp[i + j] ? v[j] : 0.f;
        } else {
            const float* mp = (const float*)mask;
            #pragma unroll
            for (int j = 0; j < 8; ++j) v[j] = (mp[i + j] != 0.f) ? v[j] : 0.f;
        }
    }
    bf16x8 o;
    #pragma unroll
    for (int j = 0; j < 8; ++j) o[j] = (__bf16)v[j];
    *reinterpret_cast<bf16x8*>(out + i) = o;
}

__global__ void prep_all(const float* __restrict__ x, __bf16* __restrict__ xb,
                         const float* __restrict__ w0, const float* __restrict__ w1,
                         const float* __restrict__ w2,
                         const void* __restrict__ m1, const void* __restrict__ m2,
                         const int* __restrict__ flag,
                         __bf16* __restrict__ w0b, __bf16* __restrict__ w1b,
                         __bf16* __restrict__ w2b) {
    const int bid = blockIdx.x;
    if (bid < 8192) {  // x -> bf16 (16M elems)
        long i = ((long)bid * blockDim.x + threadIdx.x) * 8;
        float4 a = *reinterpret_cast<const float4*>(x + i);
        float4 b = *reinterpret_cast<const float4*>(x + i + 4);
        bf16x8 o;
        o[0] = (__bf16)a.x; o[1] = (__bf16)a.y; o[2] = (__bf16)a.z; o[3] = (__bf16)a.w;
        o[4] = (__bf16)b.x; o[5] = (__bf16)b.y; o[6] = (__bf16)b.z; o[7] = (__bf16)b.w;
        *reinterpret_cast<bf16x8*>(xb + i) = o;
    } else {
        const int q = bid - 8192, wi = q >> 9, sub = q & 511;
        long i = ((long)sub * blockDim.x + threadIdx.x) * 8;
        const int mode = *flag;
        if (wi == 0)      prep_body(w0, nullptr, mode, w0b, i);
        else if (wi == 1) prep_body(w1, m1,      mode, w1b, i);
        else              prep_body(w2, m2,      mode, w2b, i);
    }
}

// ---------------------------------------------------------------------------
// 256x256-tile GEMM: C = relu(A[16384,1024] * W[1024,1024]^T + bias)
// 512 thr = 8 waves (2 row x 4 col), per-wave 128x64 out, BK=64, 16 K-tiles.
// LDS 128 KiB: A/B each [2 dbuf][BM=256 rows][64 k] bf16, XOR-swizzled.
// Pipeline: both A(t+2) and B(t+2) staged during tile t into slot tt&1
// (safe: slot reads drained by explicit lgkmcnt(0) before phase barriers).
// Steady boundary wait vmcnt(8) = leave this tile's 8 stages in flight.
// ---------------------------------------------------------------------------
__device__ __forceinline__ f32x4 mfma16(bf16x8 a, bf16x8 b, f32x4 c) {
    return __builtin_amdgcn_mfma_f32_16x16x32_bf16(a, b, c, 0, 0, 0);
}

#define MFMAQ(Q, A00, A01, A10, A11)                                        \
    __builtin_amdgcn_s_setprio(1);                                          \
    _Pragma("unroll")                                                       \
    for (int n = 0; n < 4; ++n) {                                           \
        acc[2*(Q)][n]   = mfma16(A00, b[n][0], acc[2*(Q)][n]);              \
        acc[2*(Q)][n]   = mfma16(A01, b[n][1], acc[2*(Q)][n]);              \
        acc[2*(Q)+1][n] = mfma16(A10, b[n][0], acc[2*(Q)+1][n]);            \
        acc[2*(Q)+1][n] = mfma16(A11, b[n][1], acc[2*(Q)+1][n]);            \
    }                                                                       \
    __builtin_amdgcn_s_setprio(0);

#define BAR()   __builtin_amdgcn_s_barrier(); __builtin_amdgcn_sched_barrier(0)
#define LGKM0() asm volatile("s_waitcnt lgkmcnt(0)" ::: "memory")
#define VM8()   asm volatile("s_waitcnt vmcnt(8)" ::: "memory")
#define VM0()   asm volatile("s_waitcnt vmcnt(0)" ::: "memory")

template<bool F32OUT>
__global__ __launch_bounds__(512, 2) void gemm8p(
    const __bf16* __restrict__ A, const __bf16* __restrict__ W,
    const float* __restrict__ bias,
    __bf16* __restrict__ outb, float* __restrict__ outf) {
    constexpr int NT = 16;  // K/64
    extern __shared__ char smem[];  // A: [0,64K), B: [64K,128K)

    const int t   = threadIdx.x;
    const int l   = t & 63, l15 = l & 15, lhi = l >> 4;
    const int w   = t >> 6, wr = w >> 2, wc = w & 3;

    // T1: bijective XCD swizzle (256 blocks, 8 XCDs)
    const int bid = blockIdx.x;
    const int swz = (bid & 7) * 32 + (bid >> 3);
    const int bx = swz & 3, by = swz >> 2;
    const int brow = by * 256, bcol = bx * 256;

    // staging consts: thread t covers LDS bytes [wave*1024 + lane*16) per
    // gload round; row = t>>3, in-row 16B block (t&7) XOR'd by row&7 (T2).
    const int srow = t >> 3;
    const int scol = (((t & 7) ^ ((t >> 3) & 7)) << 4) >> 1;
    const __bf16* gA = A + (size_t)(brow + srow) * 1024 + scol;
    const __bf16* gW = W + (size_t)(bcol + srow) * 1024 + scol;
    const int woff = (t & 448) * 16;  // wave*1024 (wave-uniform)

    char* const ldsA = smem;
    char* const ldsB = smem + 65536;

    auto stageAfull = [&](int d, int k0) {  // 4 instr: 256 rows x 64k
        const __bf16* g = gA + k0;
        char* p = ldsA + d * 32768 + woff;
        gload_lds16(g,          p);
        gload_lds16(g + 65536,  p + 8192);
        gload_lds16(g + 131072, p + 16384);
        gload_lds16(g + 196608, p + 24576);
    };
    auto stageBh = [&](int d, int h, int k0) {  // 2 instr: 128 rows x 64k
        const __bf16* g = gW + (size_t)h * 131072 + k0;
        char* p = ldsB + d * 32768 + h * 16384 + woff;
        gload_lds16(g, p);
        gload_lds16(g + 65536, p + 8192);
    };

    // fragment-read consts (T2 swizzled)
    const int xorm  = (l & 7) << 4;
    const int koff0 = (lhi * 16) ^ xorm;
    const int koff1 = (64 + lhi * 16) ^ xorm;
    char* const aBase = ldsA + wr * 16384 + l15 * 128;
    char* const bBase = ldsB + wc * 8192 + l15 * 128;

    f32x4 acc[8][4] = {};

    // prologue: tiles 0 and 1 (16 instr); need tile 0 -> vmcnt(8)
    stageAfull(0, 0);  stageBh(0, 0, 0);  stageBh(0, 1, 0);
    stageAfull(1, 64); stageBh(1, 0, 64); stageBh(1, 1, 64);
    VM8(); BAR();

    #pragma unroll 2
    for (int tt = 0; tt < NT; ++tt) {
        const int d  = tt & 1;
        const int k2 = (tt + 2) * 64;
        char* const aB = aBase + d * 32768;
        char* const bB = bBase + d * 32768;
        const bool st = (tt + 2 < NT);

        // ---- ph0: read all B frags + A Q0,Q1 frags; MFMA Q0 ----
        bf16x8 b[4][2];
        #pragma unroll
        for (int n = 0; n < 4; ++n) {
            b[n][0] = *(const bf16x8*)(bB + n * 2048 + koff0);
            b[n][1] = *(const bf16x8*)(bB + n * 2048 + koff1);
        }
        bf16x8 a00 = *(const bf16x8*)(aB + 0 * 2048 + koff0);
        bf16x8 a01 = *(const bf16x8*)(aB + 0 * 2048 + koff1);
        bf16x8 a10 = *(const bf16x8*)(aB + 1 * 2048 + koff0);
        bf16x8 a11 = *(const bf16x8*)(aB + 1 * 2048 + koff1);
        bf16x8 c00 = *(const bf16x8*)(aB + 2 * 2048 + koff0);
        bf16x8 c01 = *(const bf16x8*)(aB + 2 * 2048 + koff1);
        bf16x8 c10 = *(const bf16x8*)(aB + 3 * 2048 + koff0);
        bf16x8 c11 = *(const bf16x8*)(aB + 3 * 2048 + koff1);
        MFMAQ(0, a00, a01, a10, a11);
        LGKM0(); BAR();

        // ---- ph1: stage B(t+2)h0; read A Q2; MFMA Q1 ----
        if (st) stageBh(d, 0, k2);
        a00 = *(const bf16x8*)(aB + 4 * 2048 + koff0);
        a01 = *(const bf16x8*)(aB + 4 * 2048 + koff1);
        a10 = *(const bf16x8*)(aB + 5 * 2048 + koff0);
        a11 = *(const bf16x8*)(aB + 5 * 2048 + koff1);
        MFMAQ(1, c00, c01, c10, c11);
        LGKM0(); BAR();

        // ---- ph2: stage B(t+2)h1; read A Q3; MFMA Q2 ----
        if (st) stageBh(d, 1, k2);
        c00 = *(const bf16x8*)(aB + 6 * 2048 + koff0);
        c01 = *(const bf16x8*)(aB + 6 * 2048 + koff1);
        c10 = *(const bf16x8*)(aB + 7 * 2048 + koff0);
        c11 = *(const bf16x8*)(aB + 7 * 2048 + koff1);
        MFMAQ(2, a00, a01, a10, a11);
        LGKM0(); BAR();

        // ---- ph3: stage A(t+2); MFMA Q3; counted boundary wait ----
        if (st) stageAfull(d, k2);
        MFMAQ(3, c00, c01, c10, c11);
        if (tt <= NT - 3)      { VM8(); BAR(); }
        else if (tt == NT - 2) { VM0(); BAR(); }
    }

    // ---- epilogue ----
    if constexpr (F32OUT) {
        // f32 stores: 16 lanes x 4B = 64B segments, already line-aligned
        const int orow = brow + wr * 128 + lhi * 4;
        const int ocol = bcol + wc * 64 + l15;
        #pragma unroll
        for (int n = 0; n < 4; ++n) {
            const int col = ocol + n * 16;
            const float bv = bias[col];
            #pragma unroll
            for (int m = 0; m < 8; ++m) {
                const int r0 = orow + m * 16;
                #pragma unroll
                for (int r = 0; r < 4; ++r) {
                    float v = acc[m][n][r] + bv;
                    outf[(size_t)(r0 + r) * 1024 + col] = v > 0.f ? v : 0.f;
                }
            }
        }
    } else {
        // restage C tile (256x256 bf16 = 128K) in LDS, then coalesced stores
        __syncthreads();
        char* const cl = smem;
        #pragma unroll
        for (int n = 0; n < 4; ++n) {
            const int colb = (wc * 64 + n * 16 + l15) * 2;
            const float bv = bias[bcol + wc * 64 + n * 16 + l15];
            #pragma unroll
            for (int m = 0; m < 8; ++m) {
                #pragma unroll
                for (int r = 0; r < 4; ++r) {
                    const int row = wr * 128 + m * 16 + lhi * 4 + r;
                    float v = acc[m][n][r] + bv;
                    v = v > 0.f ? v : 0.f;
                    *(__bf16*)(cl + row * 512 + (colb ^ ((row & 12) << 3))) = (__bf16)v;
                }
            }
        }
        __syncthreads();
        #pragma unroll
        for (int rd = 0; rd < 16; ++rd) {
            const int off = rd * 8192 + t * 16;
            const int row = off >> 9;
            const int cb  = (off & 511) ^ ((row & 12) << 3);
            bf16x8 v = *(const bf16x8*)(cl + off);
            *(bf16x8*)((char*)outb + ((size_t)(brow + row) * 1024 + bcol) * 2 + cb) = v;
        }
    }
}

// ---------------------------------------------------------------------------
extern "C" void kernel_launch(void* const* d_in, const int* in_sizes, int n_in,
                              void* d_out, int out_size, void* d_ws, size_t ws_size,
                              hipStream_t stream) {
    const float* x  = (const float*)d_in[0];
    const float* w0 = (const float*)d_in[1];
    const float* b0 = (const float*)d_in[2];
    const float* w1 = (const float*)d_in[3];
    const float* b1 = (const float*)d_in[4];
    const void*  m1 = d_in[5];
    const float* w2 = (const float*)d_in[6];
    const float* b2 = (const float*)d_in[7];
    const void*  m2 = d_in[8];
    float* out = (float*)d_out;

    char* ws = (char*)d_ws;
    __bf16* xb  = (__bf16*)(ws);                             // 32 MiB (x, later h2)
    __bf16* h1  = (__bf16*)(ws + (size_t)32 * 1024 * 1024);  // 32 MiB
    __bf16* w0b = (__bf16*)(ws + (size_t)64 * 1024 * 1024);
    __bf16* w1b = w0b + 1024 * 1024;
    __bf16* w2b = w1b + 1024 * 1024;
    int*   flag = (int*)(w2b + 1024 * 1024);

    hipFuncSetAttribute((const void*)gemm8p<false>,
                        hipFuncAttributeMaxDynamicSharedMemorySize, 131072);
    hipFuncSetAttribute((const void*)gemm8p<true>,
                        hipFuncAttributeMaxDynamicSharedMemorySize, 131072);

    detect_mask<<<1, 64, 0, stream>>>((const unsigned char*)m1, flag);
    prep_all<<<9728, 256, 0, stream>>>(x, xb, w0, w1, w2, m1, m2, flag,
                                       w0b, w1b, w2b);

    gemm8p<false><<<256, 512, 131072, stream>>>(xb, w0b, b0, h1, nullptr);
    gemm8p<false><<<256, 512, 131072, stream>>>(h1, w1b, b1, xb, nullptr);  // h2 -> xb
    gemm8p<true ><<<256, 512, 131072, stream>>>(xb, w2b, b2, nullptr, out);
}